// Round 2
// baseline (835.177 us; speedup 1.0000x reference)
//
#include <hip/hip_runtime.h>

typedef _Float16 half8  __attribute__((ext_vector_type(8)));
typedef __fp16   fp16x2 __attribute__((ext_vector_type(2)));
typedef float    f32x16 __attribute__((ext_vector_type(16)));
typedef float    f32x4v __attribute__((ext_vector_type(4)));

#define NWG     256
#define WGSZ    512
#define CHUNKS  8          // samples per WG = CHUNKS*WGSZ = 4096; grid covers 1048576
// u32 offsets inside dynamic LDS
#define WFRAG0   0         // W2 frags: 8192 u32 (128x128 f16, MFMA A-frag order)
#define WFRAG1   8192      // W3
#define WFRAG2   16384     // W4
#define W1FRAGO  24576     // 1024 u32
#define W5FRAGO  25600     // 2048 u32
#define BIASO    27648     // b1..b4: 4*128 f32
#define B5O      28160     // b5: 2 f32
#define SMEM_U32 28164
#define SMEM_BYTES (SMEM_U32*4)

__device__ __forceinline__ unsigned pack_rn(float a, float b) {
  unsigned lo = (unsigned)__builtin_bit_cast(unsigned short, (_Float16)a);
  unsigned hi = (unsigned)__builtin_bit_cast(unsigned short, (_Float16)b);
  return lo | (hi << 16);
}
__device__ __forceinline__ unsigned pack_rtz(float a, float b) {
  fp16x2 h = __builtin_amdgcn_cvt_pkrtz(a, b);
  return __builtin_bit_cast(unsigned, h);
}
// swish = v * sigmoid(v) = v * rcp(1 + 2^(-v*log2e)) : 3 VALU + 2 trans
__device__ __forceinline__ float sw(float v) {
  float e = __builtin_amdgcn_exp2f(v * -1.44269504089f);
  return v * __builtin_amdgcn_rcpf(1.0f + e);
}
__device__ __forceinline__ half8 ldfrag(const unsigned* p) {
  uint4 u = *reinterpret_cast<const uint4*>(p);
  return __builtin_bit_cast(half8, u);
}
__device__ __forceinline__ half8 mkfrag(unsigned a, unsigned b, unsigned c, unsigned d) {
  uint4 u = make_uint4(a, b, c, d);
  return __builtin_bit_cast(half8, u);
}

// swish + f16-pack the whole accumulator (h^T layout) into pk words.
// pk[mi][ni][p] = pack(sw(acc[2p]), sw(acc[2p+1]))  (feature pair, same sample col)
__device__ __forceinline__ void layer_pack(f32x16 (&acc)[4][2], unsigned (&pk)[4][2][8]) {
#pragma unroll
  for (int mi = 0; mi < 4; ++mi)
#pragma unroll
    for (int ni = 0; ni < 2; ++ni)
#pragma unroll
      for (int p = 0; p < 8; ++p)
        pk[mi][ni][p] = pack_rtz(sw(acc[mi][ni][2*p]), sw(acc[mi][ni][2*p+1]));
}

// acc[mi][ni][4g+q] = bias[32*mi + 8*g + 4*h5 + q]  (matches D-row map (r&3)+8(r>>2)+4*h5)
__device__ __forceinline__ void bias_init(f32x16 (&acc)[4][2], const unsigned* smem,
                                          int boff_u32, int h5) {
  const float* bp = reinterpret_cast<const float*>(smem + boff_u32);
#pragma unroll
  for (int mi = 0; mi < 4; ++mi)
#pragma unroll
    for (int g = 0; g < 4; ++g) {
      f32x4v bv = *reinterpret_cast<const f32x4v*>(bp + 32*mi + 8*g + 4*h5);
#pragma unroll
      for (int q = 0; q < 4; ++q) { acc[mi][0][4*g+q] = bv[q]; acc[mi][1][4*g+q] = bv[q]; }
    }
}

// Regroup packed D-frag (source frag ks) into the two B-frags for kk=2ks, 2ks+1.
// j2=0: lo? pk0 : other(pk2); j2=2: lo? other(pk0) : pk2  (and (1,3), (4,6), (5,7))
__device__ __forceinline__ void build_b(const unsigned (&p)[8], bool lo, half8 &bf0, half8 &bf1) {
  unsigned s0 = __shfl_xor(p[0], 32), s1 = __shfl_xor(p[1], 32);
  unsigned s2 = __shfl_xor(p[2], 32), s3 = __shfl_xor(p[3], 32);
  unsigned s4 = __shfl_xor(p[4], 32), s5 = __shfl_xor(p[5], 32);
  unsigned s6 = __shfl_xor(p[6], 32), s7 = __shfl_xor(p[7], 32);
  bf0 = mkfrag(lo ? p[0] : s2, lo ? p[1] : s3, lo ? s0 : p[2], lo ? s1 : p[3]);
  bf1 = mkfrag(lo ? p[4] : s6, lo ? p[5] : s7, lo ? s4 : p[6], lo ? s5 : p[7]);
}

// One 128x128 layer: acc(new, bias-initialized) += W^T(frags in LDS) @ h^T(pk)
__device__ __forceinline__ void layer_mm(f32x16 (&acc)[4][2], const unsigned (&pk)[4][2][8],
                                         const unsigned* wb, int lane, bool lo) {
#pragma unroll
  for (int ks = 0; ks < 4; ++ks) {
    half8 bf[2][2];
#pragma unroll
    for (int ni = 0; ni < 2; ++ni) build_b(pk[ks][ni], lo, bf[ni][0], bf[ni][1]);
#pragma unroll
    for (int bb = 0; bb < 2; ++bb) {
      const int kk = 2*ks + bb;
#pragma unroll
      for (int mi = 0; mi < 4; ++mi) {
        half8 a = ldfrag(wb + ((kk*4 + mi)*64 + lane)*4);
#pragma unroll
        for (int ni = 0; ni < 2; ++ni)
          acc[mi][ni] = __builtin_amdgcn_mfma_f32_32x32x16_f16(a, bf[ni][bb], acc[mi][ni], 0, 0, 0);
      }
    }
  }
}

extern "C" __global__ __launch_bounds__(WGSZ, 2)
void mlp_k(const float* __restrict__ x, const float* __restrict__ t,
           const float* __restrict__ W1, const float* __restrict__ b1,
           const float* __restrict__ W2, const float* __restrict__ b2,
           const float* __restrict__ W3, const float* __restrict__ b3,
           const float* __restrict__ W4, const float* __restrict__ b4,
           const float* __restrict__ W5, const float* __restrict__ b5p,
           float* __restrict__ out)
{
  extern __shared__ unsigned smem[];
  const int tid = threadIdx.x;

  // ---------- stage weights (once per WG) ----------
  // mid layers: slot((kk,mi,lane,j2)) = pack(W[k][c], W[k+1][c]); k=16kk+8(lane>>5)+2j2, c=32mi+(lane&31)
  {
    const float* Wm[3] = {W2, W3, W4};
#pragma unroll
    for (int L = 0; L < 3; ++L) {
      const float* W = Wm[L];
#pragma unroll 1
      for (int it = 0; it < 16; ++it) {
        int i = it*WGSZ + tid;
        int lane = i & 63, j2 = (i >> 6) & 3, mi = (i >> 8) & 3, kk = i >> 10;
        int k = 16*kk + 8*(lane >> 5) + 2*j2;
        int c = 32*mi + (lane & 31);
        smem[L*8192 + ((kk*4 + mi)*64 + lane)*4 + j2] = pack_rn(W[k*128 + c], W[(k+1)*128 + c]);
      }
    }
  }
  // W1 (3x128), K padded to 16
#pragma unroll 1
  for (int it = 0; it < 2; ++it) {
    int i = it*WGSZ + tid;
    int lane = i & 63, j2 = (i >> 6) & 3, mi = (i >> 8) & 3;
    int k = 8*(lane >> 5) + 2*j2;
    int c = 32*mi + (lane & 31);
    float a = (k   < 3) ? W1[k*128 + c]     : 0.f;
    float b = (k+1 < 3) ? W1[(k+1)*128 + c] : 0.f;
    smem[W1FRAGO + (mi*64 + lane)*4 + j2] = pack_rn(a, b);
  }
  // W5 (128x2), M padded to 32 (rows >=2 are zero)
#pragma unroll 1
  for (int it = 0; it < 4; ++it) {
    int i = it*WGSZ + tid;
    int lane = i & 63, j2 = (i >> 6) & 3, kk = (i >> 8) & 7;
    int m = lane & 31;
    int k = 16*kk + 8*(lane >> 5) + 2*j2;
    float a = (m < 2) ? W5[k*2 + m]     : 0.f;
    float b = (m < 2) ? W5[(k+1)*2 + m] : 0.f;
    smem[W5FRAGO + (kk*64 + lane)*4 + j2] = pack_rn(a, b);
  }
  // biases
  {
    const float* bp = (tid < 128) ? b1 : (tid < 256) ? b2 : (tid < 384) ? b3 : b4;
    smem[BIASO + tid] = __builtin_bit_cast(unsigned, bp[tid & 127]);
    if (tid < 2) smem[B5O + tid] = __builtin_bit_cast(unsigned, b5p[tid]);
  }
  __syncthreads();

  // ---------- compute: no further barriers, waves free-run ----------
  const int lane = tid & 63;
  const int wv   = tid >> 6;
  const int h5   = lane >> 5;
  const int col  = lane & 31;
  const bool lo  = lane < 32;
  const float b50 = reinterpret_cast<const float*>(smem + B5O)[0];
  const float b51 = reinterpret_cast<const float*>(smem + B5O)[1];
  const float2* x2 = reinterpret_cast<const float2*>(x);

#pragma unroll 1
  for (int ch = 0; ch < CHUNKS; ++ch) {
    const int base = ((int)blockIdx.x * CHUNKS + ch) * WGSZ + wv * 64;

    float2 xa = x2[base + col];
    float2 xb = x2[base + 32 + col];
    float  ta = t[base + col];
    float  tb = t[base + 32 + col];

    // L1 B-operand: feats {x0,x1,t,0...} only in lanes h5==0, j<3
    half8 b1f[2];
    b1f[0] = mkfrag(h5 ? 0u : pack_rn(xa.x, xa.y), h5 ? 0u : pack_rn(ta, 0.f), 0u, 0u);
    b1f[1] = mkfrag(h5 ? 0u : pack_rn(xb.x, xb.y), h5 ? 0u : pack_rn(tb, 0.f), 0u, 0u);

    f32x16 acc[4][2];
    unsigned pk[4][2][8];

    // L1: h1^T = W1^T @ [x;t]^T + b1
    bias_init(acc, smem, BIASO + 0, h5);
#pragma unroll
    for (int mi = 0; mi < 4; ++mi) {
      half8 a = ldfrag(smem + W1FRAGO + (mi*64 + lane)*4);
#pragma unroll
      for (int ni = 0; ni < 2; ++ni)
        acc[mi][ni] = __builtin_amdgcn_mfma_f32_32x32x16_f16(a, b1f[ni], acc[mi][ni], 0, 0, 0);
    }

    // L2..L4
    layer_pack(acc, pk);
    bias_init(acc, smem, BIASO + 128, h5);
    layer_mm(acc, pk, smem + WFRAG0, lane, lo);

    layer_pack(acc, pk);
    bias_init(acc, smem, BIASO + 256, h5);
    layer_mm(acc, pk, smem + WFRAG1, lane, lo);

    layer_pack(acc, pk);
    bias_init(acc, smem, BIASO + 384, h5);
    layer_mm(acc, pk, smem + WFRAG2, lane, lo);

    // L5: out^T = W5^T @ h4^T + b5 (only rows 0,1 valid -> lanes h5==0, regs 0,1)
    layer_pack(acc, pk);
    f32x16 a5[2];
#pragma unroll
    for (int ni = 0; ni < 2; ++ni) {
#pragma unroll
      for (int e = 0; e < 16; ++e) a5[ni][e] = 0.f;
      a5[ni][0] = b50; a5[ni][1] = b51;
    }
#pragma unroll
    for (int ks = 0; ks < 4; ++ks) {
      half8 bf[2][2];
#pragma unroll
      for (int ni = 0; ni < 2; ++ni) build_b(pk[ks][ni], lo, bf[ni][0], bf[ni][1]);
#pragma unroll
      for (int bb = 0; bb < 2; ++bb) {
        const int kk = 2*ks + bb;
        half8 a = ldfrag(smem + W5FRAGO + (kk*64 + lane)*4);
#pragma unroll
        for (int ni = 0; ni < 2; ++ni)
          a5[ni] = __builtin_amdgcn_mfma_f32_32x32x16_f16(a, bf[ni][bb], a5[ni], 0, 0, 0);
      }
    }
    if (lo) {
#pragma unroll
      for (int ni = 0; ni < 2; ++ni) {
        int s = base + 32*ni + col;
        reinterpret_cast<float2*>(out)[s] = make_float2(a5[ni][0], a5[ni][1]);
      }
    }
  }
}

extern "C" void kernel_launch(void* const* d_in, const int* in_sizes, int n_in,
                              void* d_out, int out_size, void* d_ws, size_t ws_size,
                              hipStream_t stream) {
  (void)in_sizes; (void)n_in; (void)d_ws; (void)ws_size; (void)out_size;
  const float* x  = (const float*)d_in[0];
  const float* t  = (const float*)d_in[1];
  const float* W1 = (const float*)d_in[2];
  const float* b1 = (const float*)d_in[3];
  const float* W2 = (const float*)d_in[4];
  const float* b2 = (const float*)d_in[5];
  const float* W3 = (const float*)d_in[6];
  const float* b3 = (const float*)d_in[7];
  const float* W4 = (const float*)d_in[8];
  const float* b4 = (const float*)d_in[9];
  const float* W5 = (const float*)d_in[10];
  const float* b5 = (const float*)d_in[11];
  float* out = (float*)d_out;

  (void)hipFuncSetAttribute((const void*)mlp_k, hipFuncAttributeMaxDynamicSharedMemorySize, SMEM_BYTES);
  mlp_k<<<dim3(NWG), dim3(WGSZ), SMEM_BYTES, stream>>>(x, t, W1, b1, W2, b2, W3, b3, W4, b4, W5, b5, out);
}